// Round 1
// baseline (2314.674 us; speedup 1.0000x reference)
//
#include <hip/hip_runtime.h>
#include <math.h>

#define NBATCH 1024
#define NSEG   9
#define SLEN   36
#define NFEAT  7
#define DMODEL 128
#define DHEAD  64
#define DFFN   2048
#define EPSV   1e-5f

// ---------------------------------------------------------------------------
// GCN branch. xg = mean(x,-1).reshape(36864, 9); two-layer MLP with relu.
// Graph aggregation only affects rows 0..8 of the flat matrix (handled by
// gcn_small, which overwrites those rows after gcn_main).
// ---------------------------------------------------------------------------
__global__ __launch_bounds__(256) void gcn_main(
    const float* __restrict__ x,
    const float* __restrict__ Wg1, const float* __restrict__ bg1,
    const float* __restrict__ Wg2, const float* __restrict__ bg2,
    float* __restrict__ xgcn)
{
    __shared__ float xg[2][9];
    __shared__ float h1[2][64];
    int tid = threadIdx.x;
    int ri = tid >> 7;        // 0..1 (row within block)
    int tr = tid & 127;
    int row = blockIdx.x * 2 + ri;     // 0..36863

    if (tr < 9) {
        const float* xp = x + (row * 9 + tr) * 7;
        float s = 0.f;
        #pragma unroll
        for (int f = 0; f < 7; ++f) s += xp[f];
        xg[ri][tr] = s * (1.f / 7.f);
    }
    __syncthreads();
    if (tr < 64) {
        float acc = bg1[tr];
        #pragma unroll
        for (int j = 0; j < 9; ++j) acc += xg[ri][j] * Wg1[j * 64 + tr];
        h1[ri][tr] = fmaxf(acc, 0.f);
    }
    __syncthreads();
    {
        float acc = bg2[tr];
        #pragma unroll 8
        for (int c = 0; c < 64; ++c) acc += h1[ri][c] * Wg2[c * 128 + tr];
        xgcn[row * 128 + tr] = fmaxf(acc, 0.f);
    }
}

// Rows 0..8: all set to the mean of rows 0..8 at each layer -> identical
// output vector for all 9 rows.
__global__ void gcn_small(
    const float* __restrict__ x,
    const float* __restrict__ Wg1, const float* __restrict__ bg1,
    const float* __restrict__ Wg2, const float* __restrict__ bg2,
    float* __restrict__ xgcn)
{
    __shared__ float xgm[9];
    __shared__ float h1[64];
    int tid = threadIdx.x;
    if (tid < 9) {
        float s = 0.f;
        for (int r = 0; r < 9; ++r) {
            const float* xp = x + (r * 9 + tid) * 7;
            #pragma unroll
            for (int f = 0; f < 7; ++f) s += xp[f];
        }
        xgm[tid] = s * (1.f / 63.f);
    }
    __syncthreads();
    if (tid < 64) {
        float acc = bg1[tid];
        #pragma unroll
        for (int j = 0; j < 9; ++j) acc += xgm[j] * Wg1[j * 64 + tid];
        h1[tid] = fmaxf(acc, 0.f);
    }
    __syncthreads();
    {
        float acc = bg2[tid];
        #pragma unroll 8
        for (int c = 0; c < 64; ++c) acc += h1[c] * Wg2[c * 128 + tid];
        float v = fmaxf(acc, 0.f);
        for (int r = 0; r < 9; ++r) xgcn[r * 128 + tid] = v;
    }
}

// ---------------------------------------------------------------------------
// Conv branch. Entirely linear => mean over the 9 node-groups commutes to the
// input (9x fewer FLOPs). xc[bn,f,l] = x_flat[bn*252 + f*36 + l].
// conv1: (7->64,k5,p2)+b1 ; conv2: (64->128,k3,p1)+b2 ; BN affine.
// Writes s[b][l][c] to sbuf.
// ---------------------------------------------------------------------------
__global__ __launch_bounds__(256) void conv_branch(
    const float* __restrict__ x,
    const float* __restrict__ w1, const float* __restrict__ cb1,
    const float* __restrict__ w2, const float* __restrict__ cb2,
    const float* __restrict__ bng, const float* __restrict__ bnb,
    const float* __restrict__ bnm, const float* __restrict__ bnv,
    float* __restrict__ sbuf)
{
    __shared__ float xm[7 * 40];      // padded cols: data at [2..37]
    __shared__ float w1s[64 * 35];
    __shared__ float o1[64 * 38];     // padded cols: data at [1..36]
    int tid = threadIdx.x;
    int b = blockIdx.x;

    for (int idx = tid; idx < 7 * 40; idx += 256) xm[idx] = 0.f;
    for (int idx = tid; idx < 64 * 38; idx += 256) o1[idx] = 0.f;
    for (int idx = tid; idx < 2240; idx += 256) w1s[idx] = w1[idx];
    __syncthreads();

    const float* xb = x + (size_t)b * 2268;
    for (int idx = tid; idx < 252; idx += 256) {
        int f = idx / 36, l = idx - f * 36;
        float s = 0.f;
        #pragma unroll
        for (int n = 0; n < 9; ++n) s += xb[n * 252 + idx];
        xm[f * 40 + l + 2] = s * (1.f / 9.f);
    }
    __syncthreads();

    {   // conv1: thread -> (o = tid&63, 9 l's)
        int o = tid & 63, lh = tid >> 6;
        int l0 = lh * 9;
        float acc[9];
        float bias = cb1[o];
        #pragma unroll
        for (int r = 0; r < 9; ++r) acc[r] = bias;
        #pragma unroll
        for (int i = 0; i < 7; ++i) {
            #pragma unroll
            for (int k = 0; k < 5; ++k) {
                float w = w1s[o * 35 + i * 5 + k];
                const float* xrow = &xm[i * 40 + l0 + k];  // (l-2+k)+2 = l+k
                #pragma unroll
                for (int r = 0; r < 9; ++r) acc[r] += w * xrow[r];
            }
        }
        #pragma unroll
        for (int r = 0; r < 9; ++r) o1[o * 38 + l0 + r + 1] = acc[r];
    }
    __syncthreads();

    {   // conv2 + BN: thread -> (c = tid&127, 18 l's)
        int c = tid & 127, lh = tid >> 7;
        int l0 = lh * 18;
        float acc[18];
        #pragma unroll
        for (int r = 0; r < 18; ++r) acc[r] = 0.f;
        const float* w2c = w2 + c * 192;
        for (int i = 0; i < 64; ++i) {
            float wa = w2c[i * 3 + 0], wb = w2c[i * 3 + 1], wc = w2c[i * 3 + 2];
            const float* orow = &o1[i * 38 + l0];          // (l-1+kk)+1 = l+kk
            #pragma unroll
            for (int r = 0; r < 18; ++r)
                acc[r] += wa * orow[r] + wb * orow[r + 1] + wc * orow[r + 2];
        }
        float scale = bng[c] * rsqrtf(bnv[c] + EPSV);
        float shift = bnb[c] - bnm[c] * scale;
        float bias  = cb2[c];
        float* sb = sbuf + ((size_t)b * 36 + l0) * 128 + c;
        #pragma unroll
        for (int r = 0; r < 18; ++r)
            sb[r * 128] = (acc[r] + bias) * scale + shift;
    }
}

// ---------------------------------------------------------------------------
// One fused post-LN transformer encoder layer per batch element.
// 256 threads; thread tile = 9 rows x 2 cols (or 1 col per matrix for q/k/v).
// ---------------------------------------------------------------------------
__global__ __launch_bounds__(256) void xformer(
    float* __restrict__ sbuf,
    const float* __restrict__ ipw, const float* __restrict__ ipb,
    const float* __restrict__ opw, const float* __restrict__ opb,
    const float* __restrict__ l1g, const float* __restrict__ l1b,
    const float* __restrict__ l2g, const float* __restrict__ l2b,
    const float* __restrict__ fw1, const float* __restrict__ fb1,
    const float* __restrict__ fw2, const float* __restrict__ fb2)
{
    __shared__ float s[36][128];
    __shared__ float bufA[36][128];   // attn out -> LN temp
    __shared__ float bufB[36][128];   // cols 0..63: k ; cols 64..127: q then v ; FFN f-chunk
    __shared__ float sc[36][36];
    __shared__ float mu[36], rs[36];

    int tid = threadIdx.x;
    int b = blockIdx.x;
    float* sg = sbuf + (size_t)b * 4608;

    for (int idx = tid; idx < 4608; idx += 256) s[0][idx] = sg[idx];
    __syncthreads();

    int lane = tid & 63;
    int rt = tid >> 6;     // 0..3
    int l0 = rt * 9;
    int c0 = lane * 2;

    // ---------------- attention ----------------
    for (int h = 0; h < 2; ++h) {
        // q,k (each thread: 9 rows x 1 col d=lane)
        float aq[9], ak[9];
        #pragma unroll
        for (int r = 0; r < 9; ++r) { aq[r] = 0.f; ak[r] = 0.f; }
        const float* wq = ipw + (h * 64 + lane) * 128;
        const float* wk = ipw + (128 + h * 64 + lane) * 128;
        for (int j = 0; j < 128; j += 4) {
            float4 q4 = *(const float4*)(wq + j);
            float4 k4 = *(const float4*)(wk + j);
            #pragma unroll
            for (int r = 0; r < 9; ++r) {
                float4 s4 = *(const float4*)&s[l0 + r][j];
                aq[r] += s4.x * q4.x + s4.y * q4.y + s4.z * q4.z + s4.w * q4.w;
                ak[r] += s4.x * k4.x + s4.y * k4.y + s4.z * k4.z + s4.w * k4.w;
            }
        }
        float bq = ipb[h * 64 + lane], bk = ipb[128 + h * 64 + lane];
        #pragma unroll
        for (int r = 0; r < 9; ++r) {
            bufB[l0 + r][64 + lane] = aq[r] + bq;
            bufB[l0 + r][lane]      = ak[r] + bk;
        }
        __syncthreads();

        // scores = q @ k^T * 0.125
        for (int idx = tid; idx < 1296; idx += 256) {
            int ql = idx / 36, kl = idx - ql * 36;
            float acc = 0.f;
            #pragma unroll
            for (int dd = 0; dd < 64; dd += 4) {
                float4 q4 = *(const float4*)&bufB[ql][64 + dd];
                float4 k4 = *(const float4*)&bufB[kl][dd];
                acc += q4.x * k4.x + q4.y * k4.y + q4.z * k4.z + q4.w * k4.w;
            }
            sc[ql][kl] = acc * 0.125f;
        }
        __syncthreads();

        // v (overwrites q region; scores already consumed q)
        float av[9];
        #pragma unroll
        for (int r = 0; r < 9; ++r) av[r] = 0.f;
        const float* wv = ipw + (256 + h * 64 + lane) * 128;
        for (int j = 0; j < 128; j += 4) {
            float4 v4 = *(const float4*)(wv + j);
            #pragma unroll
            for (int r = 0; r < 9; ++r) {
                float4 s4 = *(const float4*)&s[l0 + r][j];
                av[r] += s4.x * v4.x + s4.y * v4.y + s4.z * v4.z + s4.w * v4.w;
            }
        }
        float bv = ipb[256 + h * 64 + lane];
        #pragma unroll
        for (int r = 0; r < 9; ++r) bufB[l0 + r][64 + lane] = av[r] + bv;

        // softmax rows (threads 0..35) - only touches sc
        if (tid < 36) {
            float m = -1e30f;
            for (int k = 0; k < 36; ++k) m = fmaxf(m, sc[tid][k]);
            float ssum = 0.f;
            for (int k = 0; k < 36; ++k) ssum += __expf(sc[tid][k] - m);
            float inv = 1.f / ssum;
            for (int k = 0; k < 36; ++k) sc[tid][k] = __expf(sc[tid][k] - m) * inv;
        }
        __syncthreads();

        // o = a @ v  -> bufA cols h*64..h*64+63
        float ao[9];
        #pragma unroll
        for (int r = 0; r < 9; ++r) ao[r] = 0.f;
        for (int kl = 0; kl < 36; kl += 4) {
            float v0 = bufB[kl + 0][64 + lane];
            float v1 = bufB[kl + 1][64 + lane];
            float v2 = bufB[kl + 2][64 + lane];
            float v3 = bufB[kl + 3][64 + lane];
            #pragma unroll
            for (int r = 0; r < 9; ++r) {
                float4 a4 = *(const float4*)&sc[l0 + r][kl];
                ao[r] += a4.x * v0 + a4.y * v1 + a4.z * v2 + a4.w * v3;
            }
        }
        #pragma unroll
        for (int r = 0; r < 9; ++r) bufA[l0 + r][h * 64 + lane] = ao[r];
        __syncthreads();
    }

    // ---------------- out proj + residual + LN1 ----------------
    float v0[9], v1[9];
    {
        float a0[9], a1[9];
        #pragma unroll
        for (int r = 0; r < 9; ++r) { a0[r] = 0.f; a1[r] = 0.f; }
        const float* wo0 = opw + c0 * 128;
        const float* wo1 = opw + (c0 + 1) * 128;
        for (int j = 0; j < 128; j += 4) {
            float4 wa = *(const float4*)(wo0 + j);
            float4 wb = *(const float4*)(wo1 + j);
            #pragma unroll
            for (int r = 0; r < 9; ++r) {
                float4 t4 = *(const float4*)&bufA[l0 + r][j];
                a0[r] += t4.x * wa.x + t4.y * wa.y + t4.z * wa.z + t4.w * wa.w;
                a1[r] += t4.x * wb.x + t4.y * wb.y + t4.z * wb.z + t4.w * wb.w;
            }
        }
        float bo0 = opb[c0], bo1 = opb[c0 + 1];
        #pragma unroll
        for (int r = 0; r < 9; ++r) {
            v0[r] = s[l0 + r][c0]     + a0[r] + bo0;
            v1[r] = s[l0 + r][c0 + 1] + a1[r] + bo1;
        }
    }
    __syncthreads();
    #pragma unroll
    for (int r = 0; r < 9; ++r) {
        bufA[l0 + r][c0] = v0[r];
        bufA[l0 + r][c0 + 1] = v1[r];
    }
    __syncthreads();
    if (tid < 36) {
        float m = 0.f;
        for (int j = 0; j < 128; j += 4) {
            float4 t = *(const float4*)&bufA[tid][j];
            m += t.x + t.y + t.z + t.w;
        }
        m *= (1.f / 128.f);
        float var = 0.f;
        for (int j = 0; j < 128; j += 4) {
            float4 t = *(const float4*)&bufA[tid][j];
            float dx = t.x - m, dy = t.y - m, dz = t.z - m, dw = t.w - m;
            var += dx * dx + dy * dy + dz * dz + dw * dw;
        }
        mu[tid] = m;
        rs[tid] = rsqrtf(var * (1.f / 128.f) + EPSV);
    }
    __syncthreads();
    for (int idx = tid; idx < 4608; idx += 256) {
        int l = idx >> 7, dd = idx & 127;
        s[l][dd] = (bufA[l][dd] - mu[l]) * rs[l] * l1g[dd] + l1b[dd];
    }
    __syncthreads();

    // ---------------- FFN (16 chunks of 128 neurons) ----------------
    float o0[9], o1a[9];
    #pragma unroll
    for (int r = 0; r < 9; ++r) { o0[r] = 0.f; o1a[r] = 0.f; }
    for (int ch = 0; ch < 16; ++ch) {
        int n0 = ch * 128 + c0;
        float f0[9], f1[9];
        {
            float b0 = fb1[n0], b1v = fb1[n0 + 1];
            #pragma unroll
            for (int r = 0; r < 9; ++r) { f0[r] = b0; f1[r] = b1v; }
            const float* w10 = fw1 + n0 * 128;
            const float* w11 = fw1 + (n0 + 1) * 128;
            for (int j = 0; j < 128; j += 4) {
                float4 wa = *(const float4*)(w10 + j);
                float4 wb = *(const float4*)(w11 + j);
                #pragma unroll
                for (int r = 0; r < 9; ++r) {
                    float4 s4 = *(const float4*)&s[l0 + r][j];
                    f0[r] += s4.x * wa.x + s4.y * wa.y + s4.z * wa.z + s4.w * wa.w;
                    f1[r] += s4.x * wb.x + s4.y * wb.y + s4.z * wb.z + s4.w * wb.w;
                }
            }
        }
        __syncthreads();   // prev chunk's bufB reads done
        #pragma unroll
        for (int r = 0; r < 9; ++r) {
            bufB[l0 + r][c0]     = fmaxf(f0[r], 0.f);
            bufB[l0 + r][c0 + 1] = fmaxf(f1[r], 0.f);
        }
        __syncthreads();
        const float* w20 = fw2 + c0 * 2048 + ch * 128;
        const float* w21 = fw2 + (c0 + 1) * 2048 + ch * 128;
        for (int j = 0; j < 128; j += 4) {
            float4 wa = *(const float4*)(w20 + j);
            float4 wb = *(const float4*)(w21 + j);
            #pragma unroll
            for (int r = 0; r < 9; ++r) {
                float4 f4 = *(const float4*)&bufB[l0 + r][j];
                o0[r]  += f4.x * wa.x + f4.y * wa.y + f4.z * wa.z + f4.w * wa.w;
                o1a[r] += f4.x * wb.x + f4.y * wb.y + f4.z * wb.z + f4.w * wb.w;
            }
        }
    }
    {
        float b20 = fb2[c0], b21 = fb2[c0 + 1];
        #pragma unroll
        for (int r = 0; r < 9; ++r) {
            o0[r]  += s[l0 + r][c0]     + b20;
            o1a[r] += s[l0 + r][c0 + 1] + b21;
        }
    }
    __syncthreads();
    #pragma unroll
    for (int r = 0; r < 9; ++r) {
        bufA[l0 + r][c0] = o0[r];
        bufA[l0 + r][c0 + 1] = o1a[r];
    }
    __syncthreads();
    if (tid < 36) {
        float m = 0.f;
        for (int j = 0; j < 128; j += 4) {
            float4 t = *(const float4*)&bufA[tid][j];
            m += t.x + t.y + t.z + t.w;
        }
        m *= (1.f / 128.f);
        float var = 0.f;
        for (int j = 0; j < 128; j += 4) {
            float4 t = *(const float4*)&bufA[tid][j];
            float dx = t.x - m, dy = t.y - m, dz = t.z - m, dw = t.w - m;
            var += dx * dx + dy * dy + dz * dz + dw * dw;
        }
        mu[tid] = m;
        rs[tid] = rsqrtf(var * (1.f / 128.f) + EPSV);
    }
    __syncthreads();
    for (int idx = tid; idx < 4608; idx += 256) {
        int l = idx >> 7, dd = idx & 127;
        sg[idx] = (bufA[l][dd] - mu[l]) * rs[l] * l2g[dd] + l2b[dd];
    }
}

// ---------------------------------------------------------------------------
// s += x_gcn; attention pooling over seq; linear head; LeakyReLU(0.1).
// ---------------------------------------------------------------------------
__global__ __launch_bounds__(128) void pool_head(
    const float* __restrict__ sbuf, const float* __restrict__ xgcn,
    const float* __restrict__ aww, const float* __restrict__ awb,
    const float* __restrict__ fcw, const float* __restrict__ fcb,
    float* __restrict__ out)
{
    __shared__ float sl[36][128];
    __shared__ float z[36];
    __shared__ float p[128];
    int tid = threadIdx.x;
    int b = blockIdx.x;
    const float* sg = sbuf + (size_t)b * 4608;
    const float* gg = xgcn + (size_t)b * 4608;
    for (int idx = tid; idx < 4608; idx += 128)
        sl[0][idx] = sg[idx] + gg[idx];
    __syncthreads();
    if (tid < 36) {
        float acc = awb[0];
        #pragma unroll
        for (int j = 0; j < 128; j += 4) {
            float4 s4 = *(const float4*)&sl[tid][j];
            float4 w4 = *(const float4*)(aww + j);
            acc += s4.x * w4.x + s4.y * w4.y + s4.z * w4.z + s4.w * w4.w;
        }
        z[tid] = acc;
    }
    __syncthreads();
    if (tid == 0) {
        float m = -1e30f;
        for (int k = 0; k < 36; ++k) m = fmaxf(m, z[k]);
        float ssum = 0.f;
        for (int k = 0; k < 36; ++k) ssum += __expf(z[k] - m);
        float inv = 1.f / ssum;
        for (int k = 0; k < 36; ++k) z[k] = __expf(z[k] - m) * inv;
    }
    __syncthreads();
    {
        float acc = 0.f;
        for (int l = 0; l < 36; ++l) acc += sl[l][tid] * z[l];
        p[tid] = acc;
    }
    __syncthreads();
    if (tid == 0) {
        float acc = fcb[0];
        for (int dd = 0; dd < 128; ++dd) acc += p[dd] * fcw[dd];
        out[b] = acc >= 0.f ? acc : 0.1f * acc;
    }
}

// ---------------------------------------------------------------------------
extern "C" void kernel_launch(void* const* d_in, const int* in_sizes, int n_in,
                              void* d_out, int out_size, void* d_ws, size_t ws_size,
                              hipStream_t stream)
{
    const float* x   = (const float*)d_in[0];
    const float* Wg1 = (const float*)d_in[1];
    const float* bg1 = (const float*)d_in[2];
    const float* Wg2 = (const float*)d_in[3];
    const float* bg2 = (const float*)d_in[4];
    const float* c1w = (const float*)d_in[5];
    const float* c1b = (const float*)d_in[6];
    const float* c2w = (const float*)d_in[7];
    const float* c2b = (const float*)d_in[8];
    const float* bng = (const float*)d_in[9];
    const float* bnb = (const float*)d_in[10];
    const float* bnm = (const float*)d_in[11];
    const float* bnv = (const float*)d_in[12];
    const float* ipw = (const float*)d_in[13];
    const float* ipb = (const float*)d_in[14];
    const float* opw = (const float*)d_in[15];
    const float* opb = (const float*)d_in[16];
    const float* l1g = (const float*)d_in[17];
    const float* l1b = (const float*)d_in[18];
    const float* l2g = (const float*)d_in[19];
    const float* l2b = (const float*)d_in[20];
    const float* fw1 = (const float*)d_in[21];
    const float* fb1 = (const float*)d_in[22];
    const float* fw2 = (const float*)d_in[23];
    const float* fb2 = (const float*)d_in[24];
    const float* aww = (const float*)d_in[25];
    const float* awb = (const float*)d_in[26];
    const float* fcw = (const float*)d_in[27];
    const float* fcb = (const float*)d_in[28];
    float* out = (float*)d_out;

    float* sbuf = (float*)d_ws;                       // 1024*36*128 f32
    float* xgcn = sbuf + (size_t)1024 * 36 * 128;     // 1024*36*128 f32

    gcn_main<<<18432, 256, 0, stream>>>(x, Wg1, bg1, Wg2, bg2, xgcn);
    gcn_small<<<1, 128, 0, stream>>>(x, Wg1, bg1, Wg2, bg2, xgcn);
    conv_branch<<<1024, 256, 0, stream>>>(x, c1w, c1b, c2w, c2b,
                                          bng, bnb, bnm, bnv, sbuf);
    for (int i = 0; i < 2; ++i) {
        xformer<<<1024, 256, 0, stream>>>(sbuf,
            ipw + (size_t)i * 384 * 128, ipb + (size_t)i * 384,
            opw + (size_t)i * 128 * 128, opb + (size_t)i * 128,
            l1g + (size_t)i * 128, l1b + (size_t)i * 128,
            l2g + (size_t)i * 128, l2b + (size_t)i * 128,
            fw1 + (size_t)i * 2048 * 128, fb1 + (size_t)i * 2048,
            fw2 + (size_t)i * 128 * 2048, fb2 + (size_t)i * 128);
    }
    pool_head<<<1024, 128, 0, stream>>>(sbuf, xgcn, aww, awb, fcw, fcb, out);
}

// Round 2
// 610.565 us; speedup vs baseline: 3.7910x; 3.7910x over previous
//
#include <hip/hip_runtime.h>
#include <math.h>

#define EPSV   1e-5f

typedef __attribute__((ext_vector_type(8))) short bf16x8;
typedef __attribute__((ext_vector_type(4))) float f32x4;

__device__ __forceinline__ short f2bf(float f){
    unsigned u = __float_as_uint(f);
    u += 0x7fffu + ((u >> 16) & 1u);
    return (short)(u >> 16);
}
__device__ __forceinline__ f32x4 mfma16(bf16x8 a, bf16x8 b, f32x4 c){
    return __builtin_amdgcn_mfma_f32_16x16x32_bf16(a, b, c, 0, 0, 0);
}
// swizzled LDS fragment load: row-major bf16 tile, rowBytes per row, XOR swizzle
__device__ __forceinline__ bf16x8 ldfrag(const short* base, int row, int kbyte, int rowBytes){
    int byte = row * rowBytes + kbyte;
    byte ^= (row & 7) << 4;
    return *(const bf16x8*)((const char*)base + byte);
}
__device__ __forceinline__ bf16x8 ldfragG(const short* base, int row, int kbyte, int rowBytes){
    return *(const bf16x8*)((const char*)base + (size_t)row * rowBytes + kbyte);
}
__device__ __forceinline__ void stswz(short* base, int row, int col, int rowBytes, short v){
    int byte = row * rowBytes + col * 2;
    byte ^= (row & 7) << 4;
    *(short*)((char*)base + byte) = v;
}

// ---------------------------------------------------------------------------
// fp32 -> bf16 weight conversion (runs once per launch, deterministic)
// ---------------------------------------------------------------------------
__global__ __launch_bounds__(256) void cvt_bf16(const float* __restrict__ src,
                                                short* __restrict__ dst, int n)
{
    int i = (blockIdx.x * 256 + threadIdx.x) * 4;
    if (i + 3 < n) {
        float4 v = *(const float4*)(src + i);
        short4 s;
        s.x = f2bf(v.x); s.y = f2bf(v.y); s.z = f2bf(v.z); s.w = f2bf(v.w);
        *(short4*)(dst + i) = s;
    }
}

// ---------------------------------------------------------------------------
// GCN branch (unchanged)
// ---------------------------------------------------------------------------
__global__ __launch_bounds__(256) void gcn_main(
    const float* __restrict__ x,
    const float* __restrict__ Wg1, const float* __restrict__ bg1,
    const float* __restrict__ Wg2, const float* __restrict__ bg2,
    float* __restrict__ xgcn)
{
    __shared__ float xg[2][9];
    __shared__ float h1[2][64];
    int tid = threadIdx.x;
    int ri = tid >> 7;
    int tr = tid & 127;
    int row = blockIdx.x * 2 + ri;

    if (tr < 9) {
        const float* xp = x + (row * 9 + tr) * 7;
        float s = 0.f;
        #pragma unroll
        for (int f = 0; f < 7; ++f) s += xp[f];
        xg[ri][tr] = s * (1.f / 7.f);
    }
    __syncthreads();
    if (tr < 64) {
        float acc = bg1[tr];
        #pragma unroll
        for (int j = 0; j < 9; ++j) acc += xg[ri][j] * Wg1[j * 64 + tr];
        h1[ri][tr] = fmaxf(acc, 0.f);
    }
    __syncthreads();
    {
        float acc = bg2[tr];
        #pragma unroll 8
        for (int c = 0; c < 64; ++c) acc += h1[ri][c] * Wg2[c * 128 + tr];
        xgcn[row * 128 + tr] = fmaxf(acc, 0.f);
    }
}

__global__ void gcn_small(
    const float* __restrict__ x,
    const float* __restrict__ Wg1, const float* __restrict__ bg1,
    const float* __restrict__ Wg2, const float* __restrict__ bg2,
    float* __restrict__ xgcn)
{
    __shared__ float xgm[9];
    __shared__ float h1[64];
    int tid = threadIdx.x;
    if (tid < 9) {
        float s = 0.f;
        for (int r = 0; r < 9; ++r) {
            const float* xp = x + (r * 9 + tid) * 7;
            #pragma unroll
            for (int f = 0; f < 7; ++f) s += xp[f];
        }
        xgm[tid] = s * (1.f / 63.f);
    }
    __syncthreads();
    if (tid < 64) {
        float acc = bg1[tid];
        #pragma unroll
        for (int j = 0; j < 9; ++j) acc += xgm[j] * Wg1[j * 64 + tid];
        h1[tid] = fmaxf(acc, 0.f);
    }
    __syncthreads();
    {
        float acc = bg2[tid];
        #pragma unroll 8
        for (int c = 0; c < 64; ++c) acc += h1[c] * Wg2[c * 128 + tid];
        float v = fmaxf(acc, 0.f);
        for (int r = 0; r < 9; ++r) xgcn[r * 128 + tid] = v;
    }
}

// ---------------------------------------------------------------------------
// Conv branch (unchanged; linear => mean over 9 nodes commutes to input)
// ---------------------------------------------------------------------------
__global__ __launch_bounds__(256) void conv_branch(
    const float* __restrict__ x,
    const float* __restrict__ w1, const float* __restrict__ cb1,
    const float* __restrict__ w2, const float* __restrict__ cb2,
    const float* __restrict__ bng, const float* __restrict__ bnb,
    const float* __restrict__ bnm, const float* __restrict__ bnv,
    float* __restrict__ sbuf)
{
    __shared__ float xm[7 * 40];
    __shared__ float w1s[64 * 35];
    __shared__ float o1[64 * 38];
    int tid = threadIdx.x;
    int b = blockIdx.x;

    for (int idx = tid; idx < 7 * 40; idx += 256) xm[idx] = 0.f;
    for (int idx = tid; idx < 64 * 38; idx += 256) o1[idx] = 0.f;
    for (int idx = tid; idx < 2240; idx += 256) w1s[idx] = w1[idx];
    __syncthreads();

    const float* xb = x + (size_t)b * 2268;
    for (int idx = tid; idx < 252; idx += 256) {
        int f = idx / 36, l = idx - f * 36;
        float s = 0.f;
        #pragma unroll
        for (int n = 0; n < 9; ++n) s += xb[n * 252 + idx];
        xm[f * 40 + l + 2] = s * (1.f / 9.f);
    }
    __syncthreads();

    {
        int o = tid & 63, lh = tid >> 6;
        int l0 = lh * 9;
        float acc[9];
        float bias = cb1[o];
        #pragma unroll
        for (int r = 0; r < 9; ++r) acc[r] = bias;
        #pragma unroll
        for (int i = 0; i < 7; ++i) {
            #pragma unroll
            for (int k = 0; k < 5; ++k) {
                float w = w1s[o * 35 + i * 5 + k];
                const float* xrow = &xm[i * 40 + l0 + k];
                #pragma unroll
                for (int r = 0; r < 9; ++r) acc[r] += w * xrow[r];
            }
        }
        #pragma unroll
        for (int r = 0; r < 9; ++r) o1[o * 38 + l0 + r + 1] = acc[r];
    }
    __syncthreads();

    {
        int c = tid & 127, lh = tid >> 7;
        int l0 = lh * 18;
        float acc[18];
        #pragma unroll
        for (int r = 0; r < 18; ++r) acc[r] = 0.f;
        const float* w2c = w2 + c * 192;
        for (int i = 0; i < 64; ++i) {
            float wa = w2c[i * 3 + 0], wb = w2c[i * 3 + 1], wc = w2c[i * 3 + 2];
            const float* orow = &o1[i * 38 + l0];
            #pragma unroll
            for (int r = 0; r < 18; ++r)
                acc[r] += wa * orow[r] + wb * orow[r + 1] + wc * orow[r + 2];
        }
        float scale = bng[c] * rsqrtf(bnv[c] + EPSV);
        float shift = bnb[c] - bnm[c] * scale;
        float bias  = cb2[c];
        float* sb = sbuf + ((size_t)b * 36 + l0) * 128 + c;
        #pragma unroll
        for (int r = 0; r < 18; ++r)
            sb[r * 128] = (acc[r] + bias) * scale + shift;
    }
}

// ---------------------------------------------------------------------------
// Fused transformer encoder layer, MFMA (bf16 operands, fp32 accum/LN).
// One batch element per block; 256 threads = 4 waves; M=36 padded to 48.
// ---------------------------------------------------------------------------
__global__ __launch_bounds__(256) void xformer_mfma(
    float* __restrict__ sbuf,
    const short* __restrict__ ipwb, const float* __restrict__ ipb,
    const short* __restrict__ opwb, const float* __restrict__ opb,
    const float* __restrict__ l1g, const float* __restrict__ l1b,
    const float* __restrict__ l2g, const float* __restrict__ l2b,
    const short* __restrict__ fw1b, const float* __restrict__ fb1,
    const short* __restrict__ fw2b, const float* __restrict__ fb2)
{
    __shared__ float Sf[36 * 129];   // fp32 residual stream (stride 129 -> no bank conflict)
    __shared__ short Sb[48 * 128];   // bf16 swizzled (A operand)
    __shared__ short Hb[48 * 128];   // bf16 swizzled (attn-out / FFN hidden chunk)
    __shared__ short Qb[48 * 64];
    __shared__ short Kb[48 * 64];
    __shared__ short Vt[64 * 64];    // transposed V: [d][seq]
    __shared__ short Pb[48 * 64];    // softmax probs bf16
    __shared__ float scf[36 * 50];   // fp32 scores staging

    const int tid  = threadIdx.x;
    const int wid  = tid >> 6;
    const int lane = tid & 63;
    const int lr   = lane & 15;      // fragment row/col index
    const int lg   = lane >> 4;      // k-group
    const int kbse = lg * 16;        // k-byte base within a 64B k-step
    float* sg = sbuf + (size_t)blockIdx.x * 4608;
    const f32x4 fzero = {0.f, 0.f, 0.f, 0.f};

    // ---- init: Sf, Sb (+zero pads) ----
    for (int idx = tid; idx < 4608; idx += 256) {
        int r = idx >> 7, c = idx & 127;
        float v = sg[idx];
        Sf[r * 129 + c] = v;
        stswz(Sb, r, c, 256, f2bf(v));
    }
    for (int idx = tid; idx < 1536; idx += 256) {          // Sb pad rows 36..47
        stswz(Sb, 36 + (idx >> 7), idx & 127, 256, 0);
    }
    for (int idx = tid; idx < 1024; idx += 256) {          // Vt seq cols 48..63
        stswz(Vt, idx >> 4, 48 + (idx & 15), 128, 0);
    }
    for (int idx = tid; idx < 768; idx += 256) {           // Pb pad rows 36..47
        stswz(Pb, 36 + (idx >> 6), idx & 63, 128, 0);
    }
    __syncthreads();

    // ================= attention =================
    for (int h = 0; h < 2; ++h) {
        // ---- q,k,v projections: wave wid handles n-tile wid of each ----
        {
            f32x4 acc[3][3];   // [mat][mt]
            #pragma unroll
            for (int a = 0; a < 3; ++a)
                #pragma unroll
                for (int m = 0; m < 3; ++m) acc[a][m] = fzero;
            const int wrow0 = h * 64 + wid * 16 + lr;
            #pragma unroll
            for (int ks = 0; ks < 4; ++ks) {
                bf16x8 a0 = ldfrag(Sb,      lr, ks * 64 + kbse, 256);
                bf16x8 a1 = ldfrag(Sb, 16 + lr, ks * 64 + kbse, 256);
                bf16x8 a2 = ldfrag(Sb, 32 + lr, ks * 64 + kbse, 256);
                #pragma unroll
                for (int mat = 0; mat < 3; ++mat) {
                    bf16x8 bf = ldfragG(ipwb, mat * 128 + wrow0, ks * 64 + kbse, 256);
                    acc[mat][0] = mfma16(a0, bf, acc[mat][0]);
                    acc[mat][1] = mfma16(a1, bf, acc[mat][1]);
                    acc[mat][2] = mfma16(a2, bf, acc[mat][2]);
                }
            }
            int col = wid * 16 + lr;                       // 0..63 within head
            #pragma unroll
            for (int mat = 0; mat < 3; ++mat) {
                float bias = ipb[mat * 128 + h * 64 + col];
                #pragma unroll
                for (int mt = 0; mt < 3; ++mt) {
                    f32x4 c4 = acc[mat][mt];
                    if (mat == 0) {
                        #pragma unroll
                        for (int j = 0; j < 4; ++j)
                            stswz(Qb, mt * 16 + lg * 4 + j, col, 128, f2bf(c4[j] + bias));
                    } else if (mat == 1) {
                        #pragma unroll
                        for (int j = 0; j < 4; ++j)
                            stswz(Kb, mt * 16 + lg * 4 + j, col, 128, f2bf(c4[j] + bias));
                    } else {                                // V transposed -> Vt[d][seq]
                        short4 s4;
                        s4.x = f2bf(c4[0] + bias); s4.y = f2bf(c4[1] + bias);
                        s4.z = f2bf(c4[2] + bias); s4.w = f2bf(c4[3] + bias);
                        int byte = col * 128 + (mt * 16 + lg * 4) * 2;
                        byte ^= (col & 7) << 4;
                        *(short4*)((char*)Vt + byte) = s4;
                    }
                }
            }
        }
        __syncthreads();

        // ---- scores = q @ k^T * 0.125 ----
        for (int t = wid; t < 9; t += 4) {
            int mt = t / 3, nt = t - mt * 3;
            f32x4 acc = fzero;
            #pragma unroll
            for (int ks = 0; ks < 2; ++ks) {
                bf16x8 a = ldfrag(Qb, mt * 16 + lr, ks * 64 + kbse, 128);
                bf16x8 b = ldfrag(Kb, nt * 16 + lr, ks * 64 + kbse, 128);
                acc = mfma16(a, b, acc);
            }
            int col = nt * 16 + lr;
            #pragma unroll
            for (int j = 0; j < 4; ++j) {
                int r = mt * 16 + lg * 4 + j;
                if (r < 36) scf[r * 50 + col] = acc[j] * 0.125f;
            }
        }
        __syncthreads();

        // ---- softmax rows (threads 0..35) -> Pb bf16 ----
        if (tid < 36) {
            float m = -1e30f;
            for (int k = 0; k < 36; ++k) m = fmaxf(m, scf[tid * 50 + k]);
            float ssum = 0.f;
            for (int k = 0; k < 36; ++k) ssum += __expf(scf[tid * 50 + k] - m);
            float inv = 1.f / ssum;
            for (int k = 0; k < 36; ++k)
                stswz(Pb, tid, k, 128, f2bf(__expf(scf[tid * 50 + k] - m) * inv));
            for (int k = 36; k < 64; ++k) stswz(Pb, tid, k, 128, 0);
        }
        __syncthreads();

        // ---- o = P @ V : wave wid -> d-block wid ----
        {
            f32x4 oacc[3] = {fzero, fzero, fzero};
            #pragma unroll
            for (int ks = 0; ks < 2; ++ks) {
                bf16x8 b = ldfrag(Vt, wid * 16 + lr, ks * 64 + kbse, 128);
                #pragma unroll
                for (int mt = 0; mt < 3; ++mt) {
                    bf16x8 a = ldfrag(Pb, mt * 16 + lr, ks * 64 + kbse, 128);
                    oacc[mt] = mfma16(a, b, oacc[mt]);
                }
            }
            int col = h * 64 + wid * 16 + lr;
            #pragma unroll
            for (int mt = 0; mt < 3; ++mt)
                #pragma unroll
                for (int j = 0; j < 4; ++j)
                    stswz(Hb, mt * 16 + lg * 4 + j, col, 256, f2bf(oacc[mt][j]));
        }
        __syncthreads();
    }

    // ================= out proj + residual =================
    float vout[3][2][4];
    {
        f32x4 pacc[3][2];
        #pragma unroll
        for (int m = 0; m < 3; ++m) { pacc[m][0] = fzero; pacc[m][1] = fzero; }
        #pragma unroll
        for (int ks = 0; ks < 4; ++ks) {
            bf16x8 a0 = ldfrag(Hb,      lr, ks * 64 + kbse, 256);
            bf16x8 a1 = ldfrag(Hb, 16 + lr, ks * 64 + kbse, 256);
            bf16x8 a2 = ldfrag(Hb, 32 + lr, ks * 64 + kbse, 256);
            #pragma unroll
            for (int t = 0; t < 2; ++t) {
                bf16x8 b = ldfragG(opwb, (wid * 2 + t) * 16 + lr, ks * 64 + kbse, 256);
                pacc[0][t] = mfma16(a0, b, pacc[0][t]);
                pacc[1][t] = mfma16(a1, b, pacc[1][t]);
                pacc[2][t] = mfma16(a2, b, pacc[2][t]);
            }
        }
        #pragma unroll
        for (int t = 0; t < 2; ++t) {
            int col = (wid * 2 + t) * 16 + lr;
            float bias = opb[col];
            #pragma unroll
            for (int mt = 0; mt < 3; ++mt)
                #pragma unroll
                for (int j = 0; j < 4; ++j) {
                    int r = mt * 16 + lg * 4 + j;
                    vout[mt][t][j] = (r < 36) ? pacc[mt][t][j] + bias + Sf[r * 129 + col] : 0.f;
                }
        }
    }
    __syncthreads();
    #pragma unroll
    for (int t = 0; t < 2; ++t) {
        int col = (wid * 2 + t) * 16 + lr;
        #pragma unroll
        for (int mt = 0; mt < 3; ++mt)
            #pragma unroll
            for (int j = 0; j < 4; ++j) {
                int r = mt * 16 + lg * 4 + j;
                if (r < 36) Sf[r * 129 + col] = vout[mt][t][j];
            }
    }
    __syncthreads();
    // ---- LN1 -> Sf (fp32) and Sb (bf16) ----
    if (tid < 36) {
        float m = 0.f;
        for (int c = 0; c < 128; ++c) m += Sf[tid * 129 + c];
        m *= (1.f / 128.f);
        float var = 0.f;
        for (int c = 0; c < 128; ++c) { float d = Sf[tid * 129 + c] - m; var += d * d; }
        float rstd = rsqrtf(var * (1.f / 128.f) + EPSV);
        for (int c = 0; c < 128; ++c) {
            float v = (Sf[tid * 129 + c] - m) * rstd * l1g[c] + l1b[c];
            Sf[tid * 129 + c] = v;
            stswz(Sb, tid, c, 256, f2bf(v));
        }
    }
    __syncthreads();

    // ================= FFN (16 chunks of 128 neurons) =================
    bf16x8 sa[3][4];
    #pragma unroll
    for (int mt = 0; mt < 3; ++mt)
        #pragma unroll
        for (int ks = 0; ks < 4; ++ks)
            sa[mt][ks] = ldfrag(Sb, mt * 16 + lr, ks * 64 + kbse, 256);

    f32x4 facc[3][2];
    #pragma unroll
    for (int m = 0; m < 3; ++m) { facc[m][0] = fzero; facc[m][1] = fzero; }

    for (int ch = 0; ch < 16; ++ch) {
        // FFN1: H = relu(S @ W1^T + b1), this chunk's 128 neurons
        f32x4 hacc[3][2];
        #pragma unroll
        for (int m = 0; m < 3; ++m) { hacc[m][0] = fzero; hacc[m][1] = fzero; }
        #pragma unroll
        for (int ks = 0; ks < 4; ++ks)
            #pragma unroll
            for (int t = 0; t < 2; ++t) {
                bf16x8 b = ldfragG(fw1b, ch * 128 + (wid * 2 + t) * 16 + lr,
                                   ks * 64 + kbse, 256);
                hacc[0][t] = mfma16(sa[0][ks], b, hacc[0][t]);
                hacc[1][t] = mfma16(sa[1][ks], b, hacc[1][t]);
                hacc[2][t] = mfma16(sa[2][ks], b, hacc[2][t]);
            }
        __syncthreads();   // prior chunk's FFN2 reads of Hb complete
        #pragma unroll
        for (int t = 0; t < 2; ++t) {
            int col = (wid * 2 + t) * 16 + lr;
            float bias = fb1[ch * 128 + col];
            #pragma unroll
            for (int mt = 0; mt < 3; ++mt)
                #pragma unroll
                for (int j = 0; j < 4; ++j)
                    stswz(Hb, mt * 16 + lg * 4 + j, col, 256,
                          f2bf(fmaxf(hacc[mt][t][j] + bias, 0.f)));
        }
        __syncthreads();
        // FFN2: O += H @ W2_chunk^T
        #pragma unroll
        for (int ks = 0; ks < 4; ++ks) {
            bf16x8 a0 = ldfrag(Hb,      lr, ks * 64 + kbse, 256);
            bf16x8 a1 = ldfrag(Hb, 16 + lr, ks * 64 + kbse, 256);
            bf16x8 a2 = ldfrag(Hb, 32 + lr, ks * 64 + kbse, 256);
            #pragma unroll
            for (int t = 0; t < 2; ++t) {
                bf16x8 b = ldfragG(fw2b, (wid * 2 + t) * 16 + lr,
                                   ch * 256 + ks * 64 + kbse, 4096);
                facc[0][t] = mfma16(a0, b, facc[0][t]);
                facc[1][t] = mfma16(a1, b, facc[1][t]);
                facc[2][t] = mfma16(a2, b, facc[2][t]);
            }
        }
    }

    // ---- FFN epilogue: + b2 + residual, LN2 -> global ----
    float vfin[3][2][4];
    #pragma unroll
    for (int t = 0; t < 2; ++t) {
        int col = (wid * 2 + t) * 16 + lr;
        float bias = fb2[col];
        #pragma unroll
        for (int mt = 0; mt < 3; ++mt)
            #pragma unroll
            for (int j = 0; j < 4; ++j) {
                int r = mt * 16 + lg * 4 + j;
                vfin[mt][t][j] = (r < 36) ? facc[mt][t][j] + bias + Sf[r * 129 + col] : 0.f;
            }
    }
    __syncthreads();
    #pragma unroll
    for (int t = 0; t < 2; ++t) {
        int col = (wid * 2 + t) * 16 + lr;
        #pragma unroll
        for (int mt = 0; mt < 3; ++mt)
            #pragma unroll
            for (int j = 0; j < 4; ++j) {
                int r = mt * 16 + lg * 4 + j;
                if (r < 36) Sf[r * 129 + col] = vfin[mt][t][j];
            }
    }
    __syncthreads();
    if (tid < 36) {
        float m = 0.f;
        for (int c = 0; c < 128; ++c) m += Sf[tid * 129 + c];
        m *= (1.f / 128.f);
        float var = 0.f;
        for (int c = 0; c < 128; ++c) { float d = Sf[tid * 129 + c] - m; var += d * d; }
        float rstd = rsqrtf(var * (1.f / 128.f) + EPSV);
        for (int c = 0; c < 128; ++c)
            sg[tid * 128 + c] = (Sf[tid * 129 + c] - m) * rstd * l2g[c] + l2b[c];
    }
}

// ---------------------------------------------------------------------------
// s += x_gcn; attention pooling; linear head; LeakyReLU(0.1). (unchanged)
// ---------------------------------------------------------------------------
__global__ __launch_bounds__(128) void pool_head(
    const float* __restrict__ sbuf, const float* __restrict__ xgcn,
    const float* __restrict__ aww, const float* __restrict__ awb,
    const float* __restrict__ fcw, const float* __restrict__ fcb,
    float* __restrict__ out)
{
    __shared__ float sl[36][128];
    __shared__ float z[36];
    __shared__ float p[128];
    int tid = threadIdx.x;
    int b = blockIdx.x;
    const float* sg = sbuf + (size_t)b * 4608;
    const float* gg = xgcn + (size_t)b * 4608;
    for (int idx = tid; idx < 4608; idx += 128)
        sl[0][idx] = sg[idx] + gg[idx];
    __syncthreads();
    if (tid < 36) {
        float acc = awb[0];
        #pragma unroll
        for (int j = 0; j < 128; j += 4) {
            float4 s4 = *(const float4*)&sl[tid][j];
            float4 w4 = *(const float4*)(aww + j);
            acc += s4.x * w4.x + s4.y * w4.y + s4.z * w4.z + s4.w * w4.w;
        }
        z[tid] = acc;
    }
    __syncthreads();
    if (tid == 0) {
        float m = -1e30f;
        for (int k = 0; k < 36; ++k) m = fmaxf(m, z[k]);
        float ssum = 0.f;
        for (int k = 0; k < 36; ++k) ssum += __expf(z[k] - m);
        float inv = 1.f / ssum;
        for (int k = 0; k < 36; ++k) z[k] = __expf(z[k] - m) * inv;
    }
    __syncthreads();
    {
        float acc = 0.f;
        for (int l = 0; l < 36; ++l) acc += sl[l][tid] * z[l];
        p[tid] = acc;
    }
    __syncthreads();
    if (tid == 0) {
        float acc = fcb[0];
        for (int dd = 0; dd < 128; ++dd) acc += p[dd] * fcw[dd];
        out[b] = acc >= 0.f ? acc : 0.1f * acc;
    }
}

// ---------------------------------------------------------------------------
extern "C" void kernel_launch(void* const* d_in, const int* in_sizes, int n_in,
                              void* d_out, int out_size, void* d_ws, size_t ws_size,
                              hipStream_t stream)
{
    const float* x   = (const float*)d_in[0];
    const float* Wg1 = (const float*)d_in[1];
    const float* bg1 = (const float*)d_in[2];
    const float* Wg2 = (const float*)d_in[3];
    const float* bg2 = (const float*)d_in[4];
    const float* c1w = (const float*)d_in[5];
    const float* c1b = (const float*)d_in[6];
    const float* c2w = (const float*)d_in[7];
    const float* c2b = (const float*)d_in[8];
    const float* bng = (const float*)d_in[9];
    const float* bnb = (const float*)d_in[10];
    const float* bnm = (const float*)d_in[11];
    const float* bnv = (const float*)d_in[12];
    const float* ipw = (const float*)d_in[13];
    const float* ipb = (const float*)d_in[14];
    const float* opw = (const float*)d_in[15];
    const float* opb = (const float*)d_in[16];
    const float* l1g = (const float*)d_in[17];
    const float* l1b = (const float*)d_in[18];
    const float* l2g = (const float*)d_in[19];
    const float* l2b = (const float*)d_in[20];
    const float* fw1 = (const float*)d_in[21];
    const float* fb1 = (const float*)d_in[22];
    const float* fw2 = (const float*)d_in[23];
    const float* fb2 = (const float*)d_in[24];
    const float* aww = (const float*)d_in[25];
    const float* awb = (const float*)d_in[26];
    const float* fcw = (const float*)d_in[27];
    const float* fcb = (const float*)d_in[28];
    float* out = (float*)d_out;

    float* sbuf = (float*)d_ws;                       // 1024*36*128 f32
    float* xgcn = sbuf + (size_t)1024 * 36 * 128;     // 1024*36*128 f32
    short* wb   = (short*)(xgcn + (size_t)1024 * 36 * 128);
    short* ipwb = wb;                  // 2*384*128
    short* opwb = wb + 98304;          // 2*128*128
    short* fw1b = wb + 131072;         // 2*2048*128
    short* fw2b = wb + 655360;         // 2*128*2048

    cvt_bf16<<<96,  256, 0, stream>>>(ipw, ipwb, 98304);
    cvt_bf16<<<32,  256, 0, stream>>>(opw, opwb, 32768);
    cvt_bf16<<<512, 256, 0, stream>>>(fw1, fw1b, 524288);
    cvt_bf16<<<512, 256, 0, stream>>>(fw2, fw2b, 524288);

    gcn_main<<<18432, 256, 0, stream>>>(x, Wg1, bg1, Wg2, bg2, xgcn);
    gcn_small<<<1, 128, 0, stream>>>(x, Wg1, bg1, Wg2, bg2, xgcn);
    conv_branch<<<1024, 256, 0, stream>>>(x, c1w, c1b, c2w, c2b,
                                          bng, bnb, bnm, bnv, sbuf);
    for (int i = 0; i < 2; ++i) {
        xformer_mfma<<<1024, 256, 0, stream>>>(sbuf,
            ipwb + (size_t)i * 49152, ipb + (size_t)i * 384,
            opwb + (size_t)i * 16384, opb + (size_t)i * 128,
            l1g + (size_t)i * 128, l1b + (size_t)i * 128,
            l2g + (size_t)i * 128, l2b + (size_t)i * 128,
            fw1b + (size_t)i * 262144, fb1 + (size_t)i * 2048,
            fw2b + (size_t)i * 262144, fb2 + (size_t)i * 128);
    }
    pool_head<<<1024, 128, 0, stream>>>(sbuf, xgcn, aww, awb, fcw, fcb, out);
}